// Round 7
// baseline (348.030 us; speedup 1.0000x reference)
//
#include <hip/hip_runtime.h>

using bf16x8 = __attribute__((ext_vector_type(8))) __bf16;
using f32x4  = __attribute__((ext_vector_type(4))) float;

#define C_ 64
#define S_ 128
#define H_ 2048
#define M_ 8192

__device__ __forceinline__ unsigned short f2bf(float f) {
  unsigned u = __float_as_uint(f);
  u = u + 0x7fffu + ((u >> 16) & 1u);   // RNE
  return (unsigned short)(u >> 16);
}
__device__ __forceinline__ float bf2f(unsigned short h) {
  return __uint_as_float(((unsigned)h) << 16);
}

// async global->LDS, 16 B per lane; LDS dest = uniform base + lane*16
__device__ __forceinline__ void glds16(const unsigned short* g, unsigned short* l) {
  __builtin_amdgcn_global_load_lds(
      (const __attribute__((address_space(1))) void*)g,
      (__attribute__((address_space(3))) void*)l, 16, 0, 0);
}

// ---- fused: split x (blocks 0..16383) | split+transpose W (16384..17407) | zero G ----
__global__ void k_split_all(const float* __restrict__ x,
                            unsigned short* __restrict__ xh,
                            unsigned short* __restrict__ xl,
                            const float* __restrict__ W,
                            unsigned short* __restrict__ Wth,
                            unsigned short* __restrict__ Wtl,
                            float* __restrict__ G) {
  __shared__ float Ts[64][68];
  const int b = blockIdx.x;
  const int t = threadIdx.x;
  if (b < 16384) {
    int idx = b * 256 + t;
    float4 v = ((const float4*)x)[idx];
    float a[4] = {v.x, v.y, v.z, v.w};
    unsigned short h[4], l[4];
#pragma unroll
    for (int q = 0; q < 4; ++q) {
      h[q] = f2bf(a[q]);
      l[q] = f2bf(a[q] - bf2f(h[q]));
    }
    ((ushort4*)xh)[idx] = make_ushort4(h[0], h[1], h[2], h[3]);
    ((ushort4*)xl)[idx] = make_ushort4(l[0], l[1], l[2], l[3]);
  } else if (b < 17408) {
    const int bb = b - 16384;
    const int k0 = (bb & 31) * 64, n0 = (bb >> 5) * 64;
#pragma unroll
    for (int p = 0; p < 4; ++p) {
      int idx = t + p * 256;
      int r = idx >> 4, c4 = (idx & 15) * 4;
      *(float4*)&Ts[r][c4] = *(const float4*)(W + (size_t)(k0 + r) * H_ + n0 + c4);
    }
    __syncthreads();
#pragma unroll
    for (int p = 0; p < 4; ++p) {
      int idx = t + p * 256;
      int rr = idx >> 4, cc = (idx & 15) * 4;   // rr = n-local, cc = k-local
      unsigned short h[4], l[4];
#pragma unroll
      for (int q = 0; q < 4; ++q) {
        float f = Ts[cc + q][rr];
        h[q] = f2bf(f);
        l[q] = f2bf(f - bf2f(h[q]));
      }
      size_t o = (size_t)(n0 + rr) * H_ + k0 + cc;
      *(ushort4*)(Wth + o) = make_ushort4(h[0], h[1], h[2], h[3]);
      *(ushort4*)(Wtl + o) = make_ushort4(l[0], l[1], l[2], l[3]);
    }
  } else {
    const int bb = b - 17408;   // 1024 blocks * 256 threads * 16 B = 4 MiB
    ((float4*)G)[bb * 256 + t] = (float4){0.f, 0.f, 0.f, 0.f};
  }
}

// ------- 3-term split-bf16 MFMA GEMM, 1:1 interleaved read/MFMA stream -------
// R7: R6 skeleton (256x128 tile, 8 waves 4x2, 3 LDS buffers, counted
// vmcnt(6), asm ds_reads, reg double-buffer). R6 evidence: dbuf materialized
// (volatile asm can't sink; operands live in AGPRs) yet per-tile time is
// still additive (3160 ~ 1536 LDS + 1862 MFMA). Surviving theory: ISSUE
// PILEUP -- a 16-read burst from all 8 waves overflows the LDS queue, waves
// stall in the in-order issue stage and can't reach their MFMAs. Fix = the
// AITER interleave: 8 groups of {2 ds_reads -> 6 MFMAs}; max 2 reads
// outstanding per wave before it returns to MFMA issue, so the LDS pipe
// drains UNDER the MFMA stream.
#define TILE_USH 24576            // 48 KiB per buffer in ushorts
#define OFF_AH 0                  // byte offsets within buffer:
#define OFF_AL 8192               //   AH 0, AL 16384, BH 32768, BL 40960
#define OFF_BH 16384
#define OFF_BL 20480

#define DSREAD(dst, addr, OFFLIT) \
  asm volatile("ds_read_b128 %0, %1 offset:" OFFLIT : "=v"(dst) : "v"(addr))

#define MF3(I, J, CAH, CAL, CBH, CBL)                                                          \
  acc[I][J] = __builtin_amdgcn_mfma_f32_16x16x32_bf16(CAH[I], CBH[J], acc[I][J], 0, 0, 0);     \
  acc[I][J] = __builtin_amdgcn_mfma_f32_16x16x32_bf16(CAH[I], CBL[J], acc[I][J], 0, 0, 0);     \
  acc[I][J] = __builtin_amdgcn_mfma_f32_16x16x32_bf16(CAL[I], CBH[J], acc[I][J], 0, 0, 0);

#define SB __builtin_amdgcn_sched_barrier(0)

// interleaved tile: reads R-set (tile t+1) 2-at-a-time between 6-MFMA chunks
// consuming C-set (tile t)
#define TILE_ILV(RAH, RAL, RBH, RBL, CAH, CAL, CBH, CBL, off_ush)        \
  do {                                                                   \
    const unsigned _ab = aAb + (unsigned)(off_ush) * 2u;                 \
    const unsigned _bb = aBb + (unsigned)(off_ush) * 2u;                 \
    __builtin_amdgcn_s_setprio(1);                                       \
    DSREAD(RAH[0], _ab, "0");     DSREAD(RAH[1], _ab, "1024");     SB;   \
    MF3(0, 0, CAH, CAL, CBH, CBL) MF3(0, 1, CAH, CAL, CBH, CBL)    SB;   \
    DSREAD(RAH[2], _ab, "2048");  DSREAD(RAH[3], _ab, "3072");     SB;   \
    MF3(0, 2, CAH, CAL, CBH, CBL) MF3(0, 3, CAH, CAL, CBH, CBL)    SB;   \
    DSREAD(RAL[0], _ab, "16384"); DSREAD(RAL[1], _ab, "17408");    SB;   \
    MF3(1, 0, CAH, CAL, CBH, CBL) MF3(1, 1, CAH, CAL, CBH, CBL)    SB;   \
    DSREAD(RAL[2], _ab, "18432"); DSREAD(RAL[3], _ab, "19456");    SB;   \
    MF3(1, 2, CAH, CAL, CBH, CBL) MF3(1, 3, CAH, CAL, CBH, CBL)    SB;   \
    DSREAD(RBH[0], _bb, "32768"); DSREAD(RBH[1], _bb, "33792");    SB;   \
    MF3(2, 0, CAH, CAL, CBH, CBL) MF3(2, 1, CAH, CAL, CBH, CBL)    SB;   \
    DSREAD(RBH[2], _bb, "34816"); DSREAD(RBH[3], _bb, "35840");    SB;   \
    MF3(2, 2, CAH, CAL, CBH, CBL) MF3(2, 3, CAH, CAL, CBH, CBL)    SB;   \
    DSREAD(RBL[0], _bb, "40960"); DSREAD(RBL[1], _bb, "41984");    SB;   \
    MF3(3, 0, CAH, CAL, CBH, CBL) MF3(3, 1, CAH, CAL, CBH, CBL)    SB;   \
    DSREAD(RBL[2], _bb, "43008"); DSREAD(RBL[3], _bb, "44032");    SB;   \
    MF3(3, 2, CAH, CAL, CBH, CBL) MF3(3, 3, CAH, CAL, CBH, CBL)    SB;   \
    __builtin_amdgcn_s_setprio(0);                                       \
  } while (0)

#define LOADSET_ASM(AH, AL, BH, BL, off_ush)                      \
  do {                                                            \
    unsigned _ab = aAb + (unsigned)(off_ush) * 2u;                \
    unsigned _bb = aBb + (unsigned)(off_ush) * 2u;                \
    DSREAD(AH[0], _ab, "0");     DSREAD(AH[1], _ab, "1024");      \
    DSREAD(AH[2], _ab, "2048");  DSREAD(AH[3], _ab, "3072");      \
    DSREAD(AL[0], _ab, "16384"); DSREAD(AL[1], _ab, "17408");     \
    DSREAD(AL[2], _ab, "18432"); DSREAD(AL[3], _ab, "19456");     \
    DSREAD(BH[0], _bb, "32768"); DSREAD(BH[1], _bb, "33792");     \
    DSREAD(BH[2], _bb, "34816"); DSREAD(BH[3], _bb, "35840");     \
    DSREAD(BL[0], _bb, "40960"); DSREAD(BL[1], _bb, "41984");     \
    DSREAD(BL[2], _bb, "43008"); DSREAD(BL[3], _bb, "44032");     \
  } while (0)

#define MFMASET(AH, AL, BH, BL)                                                                  \
  do {                                                                                           \
    __builtin_amdgcn_s_setprio(1);                                                               \
    _Pragma("unroll") for (int i = 0; i < 4; ++i)                                                \
        _Pragma("unroll") for (int j = 0; j < 4; ++j) {                                          \
      acc[i][j] = __builtin_amdgcn_mfma_f32_16x16x32_bf16(AH[i], BH[j], acc[i][j], 0, 0, 0);     \
      acc[i][j] = __builtin_amdgcn_mfma_f32_16x16x32_bf16(AH[i], BL[j], acc[i][j], 0, 0, 0);     \
      acc[i][j] = __builtin_amdgcn_mfma_f32_16x16x32_bf16(AL[i], BH[j], acc[i][j], 0, 0, 0);     \
    }                                                                                            \
    __builtin_amdgcn_s_setprio(0);                                                               \
  } while (0)

__global__ __launch_bounds__(512, 2) void k_gemm3(
    const unsigned short* __restrict__ Ah, const unsigned short* __restrict__ Al,
    const unsigned short* __restrict__ Bh, const unsigned short* __restrict__ Bl,
    unsigned short* __restrict__ Eh, unsigned short* __restrict__ El) {
  __shared__ unsigned short lds[3 * TILE_USH];
  const int t = threadIdx.x;
  const int lane = t & 63, wid = t >> 6;     // 8 waves
  const int wm = wid >> 1, wn = wid & 1;     // 4x2 wave grid, wave tile 64x64
  const int l16 = lane & 15, quad = lane >> 4;

  // bijective XCD remap of the 512-block grid
  const int lin = blockIdx.x + (blockIdx.y << 5);
  const int xcd = lin & 7, slot = lin >> 3;
  const int bm = ((xcd >> 1) << 3) + (slot >> 3);   // 0..31
  const int bn = ((xcd & 1) << 3) + (slot & 7);     // 0..15

  // staging addresses (pre-swizzled global source, linear LDS dest)
  const int rl = lane >> 2;
  const int gg8 = (((lane & 3) ^ ((rl >> 1) & 3)) << 3);
  const unsigned short* gAh0 = Ah + (size_t)(bm * 256 + wid * 16 + rl) * H_ + gg8;
  const unsigned short* gAl0 = Al + (size_t)(bm * 256 + wid * 16 + rl) * H_ + gg8;
  const unsigned short* gAh1 = gAh0 + (size_t)128 * H_;
  const unsigned short* gAl1 = gAl0 + (size_t)128 * H_;
  const unsigned short* gBh  = Bh + (size_t)(bn * 128 + wid * 16 + rl) * H_ + gg8;
  const unsigned short* gBl  = Bl + (size_t)(bn * 128 + wid * 16 + rl) * H_ + gg8;
  const int dA0 = wid * 512;        // chunk = 16 rows * 32 ushorts = 1 KiB
  const int dA1 = dA0 + 4096;       // chunk wid+8
  const int dB  = wid * 512;

  // read-side swizzled fragment offsets (ushort units, 0-conflict pattern)
  const int colq = ((quad ^ ((l16 >> 1) & 3)) << 3);
  const int rA = (wm * 64 + l16) * 32 + colq;
  const int rB = (wn * 64 + l16) * 32 + colq;
  // byte addresses for asm ds_read (generic LDS ptr low 32 bits = LDS offset)
  const unsigned ldsb = (unsigned)(uintptr_t)&lds[0];
  const unsigned aAb = ldsb + (unsigned)rA * 2u;
  const unsigned aBb = ldsb + (unsigned)rB * 2u;

  f32x4 acc[4][4];
#pragma unroll
  for (int i = 0; i < 4; ++i)
#pragma unroll
    for (int j = 0; j < 4; ++j) acc[i][j] = (f32x4)0.f;

  auto stage6 = [&](int bo, int k) {
    glds16(gAh0 + k, &lds[bo + OFF_AH + dA0]);
    glds16(gAh1 + k, &lds[bo + OFF_AH + dA1]);
    glds16(gAl0 + k, &lds[bo + OFF_AL + dA0]);
    glds16(gAl1 + k, &lds[bo + OFF_AL + dA1]);
    glds16(gBh + k,  &lds[bo + OFF_BH + dB]);
    glds16(gBl + k,  &lds[bo + OFF_BL + dB]);
  };

  // prologue: tiles 0,1 in flight; wait tile 0; asm-load its fragments
  stage6(0, 0);
  stage6(TILE_USH, 32);
  asm volatile("s_waitcnt vmcnt(6)" ::: "memory");
  __builtin_amdgcn_s_barrier();
  __builtin_amdgcn_sched_barrier(0);

  bf16x8 ahA[4], alA[4], bhA[4], blA[4];
  bf16x8 ahB[4], alB[4], bhB[4], blB[4];
  LOADSET_ASM(ahA, alA, bhA, blA, 0);

  int stage_off = 2 * TILE_USH;   // buffer of tile tt+2 at iter tt
  int read_off  = TILE_USH;       // buffer of tile tt+1 at iter tt

#pragma unroll 1
  for (int tt = 0; tt < 62; tt += 2) {
    // ---- tile tt: stage tt+2; interleave {reads of tt+1 (B-set)} with
    //      {MFMAs of tt (A-set)} ----
    stage6(stage_off, (tt + 2) * 32);
    stage_off += TILE_USH; if (stage_off == 3 * TILE_USH) stage_off = 0;
    asm volatile("s_waitcnt vmcnt(6) lgkmcnt(0)" ::: "memory");
    __builtin_amdgcn_s_barrier();
    __builtin_amdgcn_sched_barrier(0);
    TILE_ILV(ahB, alB, bhB, blB, ahA, alA, bhA, blA, read_off);
    read_off += TILE_USH; if (read_off == 3 * TILE_USH) read_off = 0;
    // ---- tile tt+1: stage tt+3; reads of tt+2 (A-set) vs MFMAs of tt+1 ----
    stage6(stage_off, (tt + 3) * 32);
    stage_off += TILE_USH; if (stage_off == 3 * TILE_USH) stage_off = 0;
    asm volatile("s_waitcnt vmcnt(6) lgkmcnt(0)" ::: "memory");
    __builtin_amdgcn_s_barrier();
    __builtin_amdgcn_sched_barrier(0);
    TILE_ILV(ahA, alA, bhA, blA, ahB, alB, bhB, blB, read_off);
    read_off += TILE_USH; if (read_off == 3 * TILE_USH) read_off = 0;
  }

  // tile 62: drain everything, issue reads for tile 63, MFMA A-set
  asm volatile("s_waitcnt vmcnt(0) lgkmcnt(0)" ::: "memory");
  __builtin_amdgcn_s_barrier();
  __builtin_amdgcn_sched_barrier(0);
  LOADSET_ASM(ahB, alB, bhB, blB, read_off);
  __builtin_amdgcn_sched_barrier(0);
  MFMASET(ahA, alA, bhA, blA);
  // tile 63: wait its asm reads, then MFMA B-set
  asm volatile("s_waitcnt lgkmcnt(0)" ::: "memory");
  __builtin_amdgcn_sched_barrier(0);
  MFMASET(ahB, alB, bhB, blB);

  // epilogue: split-bf16 store of E
#pragma unroll
  for (int i = 0; i < 4; ++i) {
    const int row0 = bm * 256 + wm * 64 + i * 16 + quad * 4;
#pragma unroll
    for (int j = 0; j < 4; ++j) {
      const int col = bn * 128 + wn * 64 + j * 16 + l16;
#pragma unroll
      for (int r = 0; r < 4; ++r) {
        float v = acc[i][j][r];
        unsigned short hh = f2bf(v);
        unsigned short ll = f2bf(v - bf2f(hh));
        Eh[(size_t)(row0 + r) * H_ + col] = hh;
        El[(size_t)(row0 + r) * H_ + col] = ll;
      }
    }
  }
}

// ---- MFMA Gram: G[c] += Eh*Eh^T + Eh*El^T + El*Eh^T; K split 8-way
//      (grid (8,64)): 2 blocks/CU co-resident so one block's vmcnt(0)
//      stall overlaps the other's MFMAs. ----
__global__ __launch_bounds__(256, 4) void k_gram_mfma(
    const unsigned short* __restrict__ Eh, const unsigned short* __restrict__ El,
    float* __restrict__ G) {
  __shared__ unsigned short sb[2][16384];   // per buffer: H 8192, L 8192
  const int t = threadIdx.x;
  const int kc = blockIdx.x;   // 0..7, each covers ONE 256-wide K chunk
  const int cc = blockIdx.y;   // capsule
  const int lane = t & 63, wid = t >> 6;
  const int wm = wid >> 1, wn = wid & 1;
  const int l16 = lane & 15, quad = lane >> 4;

  const int rl = lane >> 2;
  const int gg = (lane & 3) ^ ((rl >> 1) & 3);
  const int c0 = wid * 2, c1 = c0 + 1;
  const unsigned short* gH0 = Eh + (size_t)(cc * 128 + c0 * 16 + rl) * H_ + gg * 8;
  const unsigned short* gH1 = Eh + (size_t)(cc * 128 + c1 * 16 + rl) * H_ + gg * 8;
  const unsigned short* gL0 = El + (size_t)(cc * 128 + c0 * 16 + rl) * H_ + gg * 8;
  const unsigned short* gL1 = El + (size_t)(cc * 128 + c1 * 16 + rl) * H_ + gg * 8;
  const int dH0 = c0 * 512, dH1 = c1 * 512;

  const int swz = ((l16 >> 1) & 3);
  const int colq = ((quad ^ swz) * 8);

  f32x4 acc[4][4];
#pragma unroll
  for (int i = 0; i < 4; ++i)
#pragma unroll
    for (int j = 0; j < 4; ++j) acc[i][j] = (f32x4)0.f;

  auto stage4 = [&](int buf, int k) {
    glds16(gH0 + k, &sb[buf][dH0]);
    glds16(gH1 + k, &sb[buf][dH1]);
    glds16(gL0 + k, &sb[buf][8192 + dH0]);
    glds16(gL1 + k, &sb[buf][8192 + dH1]);
  };

  const int kbeg = kc * 256;           // one 256-wide chunk = 8 steps
  stage4(0, kbeg);
  asm volatile("s_waitcnt vmcnt(0)" ::: "memory");
  __builtin_amdgcn_s_barrier();

  int cur = 0;
#pragma unroll 1
  for (int s = 0; s < 8; ++s) {
    if (s < 7) stage4(cur ^ 1, kbeg + (s + 1) * 32);
    const unsigned short* sH = &sb[cur][0];
    const unsigned short* sL = &sb[cur][8192];
    bf16x8 ah[4], al[4], bh[4], bl[4];
#pragma unroll
    for (int i = 0; i < 4; ++i) {
      const int ra = (wm * 64 + i * 16 + l16) * 32;
      const int rb = (wn * 64 + i * 16 + l16) * 32;
      ah[i] = *(const bf16x8*)&sH[ra + colq];
      al[i] = *(const bf16x8*)&sL[ra + colq];
      bh[i] = *(const bf16x8*)&sH[rb + colq];
      bl[i] = *(const bf16x8*)&sL[rb + colq];
    }
    __builtin_amdgcn_s_setprio(1);
#pragma unroll
    for (int i = 0; i < 4; ++i)
#pragma unroll
      for (int j = 0; j < 4; ++j) {
        acc[i][j] = __builtin_amdgcn_mfma_f32_16x16x32_bf16(ah[i], bh[j], acc[i][j], 0, 0, 0);
        acc[i][j] = __builtin_amdgcn_mfma_f32_16x16x32_bf16(ah[i], bl[j], acc[i][j], 0, 0, 0);
        acc[i][j] = __builtin_amdgcn_mfma_f32_16x16x32_bf16(al[i], bh[j], acc[i][j], 0, 0, 0);
      }
    __builtin_amdgcn_s_setprio(0);
    if (s < 7) {
      asm volatile("s_waitcnt vmcnt(0) lgkmcnt(0)" ::: "memory");
      __builtin_amdgcn_s_barrier();
    }
    cur ^= 1;
  }

  float* Gc = G + (size_t)cc * S_ * S_;
#pragma unroll
  for (int i = 0; i < 4; ++i) {
    const int row0 = wm * 64 + i * 16 + quad * 4;
#pragma unroll
    for (int j = 0; j < 4; ++j) {
      const int col = wn * 64 + j * 16 + l16;
#pragma unroll
      for (int r = 0; r < 4; ++r)
        atomicAdd(&Gc[(row0 + r) * S_ + col], acc[i][j][r]);
    }
  }
}

// ---- fused routing + projection: each block redoes its capsule's routing ----
__global__ void k_out2(const unsigned short* __restrict__ Eh,
                       const unsigned short* __restrict__ El,
                       const float* __restrict__ G, float* __restrict__ out) {
  const int c = blockIdx.y;
  const int s = threadIdx.x & 127;
  __shared__ float dsh[128];
  __shared__ float red[128];
  __shared__ float wsh[128];
  const float* Gc = G + (size_t)c * S_ * S_;
  float b = 0.f;
  for (int it = 0; it < 3; ++it) {
    red[s] = b; __syncthreads();
    for (int off = 64; off > 0; off >>= 1) {
      if (s < off) red[s] = fmaxf(red[s], red[s + off]);
      __syncthreads();
    }
    float mx = red[0]; __syncthreads();
    float ev = expf(b - mx);
    red[s] = ev; __syncthreads();
    for (int off = 64; off > 0; off >>= 1) {
      if (s < off) red[s] = red[s] + red[s + off];
      __syncthreads();
    }
    float Z = red[0]; __syncthreads();
    float d = ev / Z;
    dsh[s] = d; __syncthreads();
    float y = 0.f;   // (G d)_s via symmetric-column reads
#pragma unroll 8
    for (int j = 0; j < S_; ++j) y = fmaf(Gc[j * S_ + s], dsh[j], y);
    red[s] = d * y; __syncthreads();
    for (int off = 64; off > 0; off >>= 1) {
      if (s < off) red[s] = red[s] + red[s + off];
      __syncthreads();
    }
    float sq = red[0]; __syncthreads();
    float coeff = sq / (1.f + sq) / sqrtf(sq + 1e-9f);
    if (it == 2) wsh[s] = coeff * d;
    else b += coeff * y;
  }
  __syncthreads();

  // projection: out[c,h] = sum_s wsh[s] * (Eh+El)[c,s,h], 2 h per thread
  const int h2 = blockIdx.x * 256 + threadIdx.x;   // dword index, grid.x = 4
  const unsigned* Ph = (const unsigned*)(Eh + (size_t)c * S_ * H_) + h2;
  const unsigned* Pl = (const unsigned*)(El + (size_t)c * S_ * H_) + h2;
  float a0 = 0.f, a1 = 0.f;
#pragma unroll 8
  for (int ss = 0; ss < S_; ++ss) {
    unsigned uh = Ph[(size_t)ss * (H_ / 2)];
    unsigned ul = Pl[(size_t)ss * (H_ / 2)];
    a0 = fmaf(wsh[ss], bf2f((unsigned short)uh) + bf2f((unsigned short)ul), a0);
    a1 = fmaf(wsh[ss], bf2f((unsigned short)(uh >> 16)) + bf2f((unsigned short)(ul >> 16)), a1);
  }
  ((float2*)(out + (size_t)c * H_))[h2] = make_float2(a0, a1);
}

extern "C" void kernel_launch(void* const* d_in, const int* in_sizes, int n_in,
                              void* d_out, int out_size, void* d_ws, size_t ws_size,
                              hipStream_t stream) {
  (void)in_sizes; (void)n_in; (void)out_size; (void)ws_size;
  const float* x = (const float*)d_in[0];
  const float* W = (const float*)d_in[1];
  float* out = (float*)d_out;
  char* ws = (char*)d_ws;

  unsigned short* xh  = (unsigned short*)(ws);                 // 32 MiB
  unsigned short* xl  = (unsigned short*)(ws + 33554432);      // 32 MiB
  unsigned short* Wth = (unsigned short*)(ws + 67108864);      // 8 MiB
  unsigned short* Wtl = (unsigned short*)(ws + 75497472);      // 8 MiB
  unsigned short* Eh  = (unsigned short*)(ws + 83886080);      // 32 MiB
  unsigned short* El  = (unsigned short*)(ws + 117440512);     // 32 MiB
  float*          G   = (float*)(ws + 150994944);              // 4 MiB

  k_split_all<<<dim3(18432), 256, 0, stream>>>(x, xh, xl, W, Wth, Wtl, G);
  k_gemm3<<<dim3(32, 16), 512, 0, stream>>>(xh, xl, Wth, Wtl, Eh, El);
  k_gram_mfma<<<dim3(8, 64), 256, 0, stream>>>(Eh, El, G);
  k_out2<<<dim3(4, 64), 256, 0, stream>>>(Eh, El, G, out);
}

// Round 8
// 321.063 us; speedup vs baseline: 1.0840x; 1.0840x over previous
//
#include <hip/hip_runtime.h>

using bf16x8 = __attribute__((ext_vector_type(8))) __bf16;
using f32x4  = __attribute__((ext_vector_type(4))) float;

#define C_ 64
#define S_ 128
#define H_ 2048
#define M_ 8192

__device__ __forceinline__ unsigned short f2bf(float f) {
  unsigned u = __float_as_uint(f);
  u = u + 0x7fffu + ((u >> 16) & 1u);   // RNE
  return (unsigned short)(u >> 16);
}
__device__ __forceinline__ float bf2f(unsigned short h) {
  return __uint_as_float(((unsigned)h) << 16);
}

// async global->LDS, 16 B per lane; LDS dest = uniform base + lane*16
__device__ __forceinline__ void glds16(const unsigned short* g, unsigned short* l) {
  __builtin_amdgcn_global_load_lds(
      (const __attribute__((address_space(1))) void*)g,
      (__attribute__((address_space(3))) void*)l, 16, 0, 0);
}

// ---- fused: split x (blocks 0..16383) | split+transpose W (16384..17407) ----
// (G zero-init dropped: gram now writes full partial tiles with plain stores)
__global__ void k_split_all(const float* __restrict__ x,
                            unsigned short* __restrict__ xh,
                            unsigned short* __restrict__ xl,
                            const float* __restrict__ W,
                            unsigned short* __restrict__ Wth,
                            unsigned short* __restrict__ Wtl) {
  __shared__ float Ts[64][68];
  const int b = blockIdx.x;
  const int t = threadIdx.x;
  if (b < 16384) {
    int idx = b * 256 + t;
    float4 v = ((const float4*)x)[idx];
    float a[4] = {v.x, v.y, v.z, v.w};
    unsigned short h[4], l[4];
#pragma unroll
    for (int q = 0; q < 4; ++q) {
      h[q] = f2bf(a[q]);
      l[q] = f2bf(a[q] - bf2f(h[q]));
    }
    ((ushort4*)xh)[idx] = make_ushort4(h[0], h[1], h[2], h[3]);
    ((ushort4*)xl)[idx] = make_ushort4(l[0], l[1], l[2], l[3]);
  } else {
    const int bb = b - 16384;
    const int k0 = (bb & 31) * 64, n0 = (bb >> 5) * 64;
#pragma unroll
    for (int p = 0; p < 4; ++p) {
      int idx = t + p * 256;
      int r = idx >> 4, c4 = (idx & 15) * 4;
      *(float4*)&Ts[r][c4] = *(const float4*)(W + (size_t)(k0 + r) * H_ + n0 + c4);
    }
    __syncthreads();
#pragma unroll
    for (int p = 0; p < 4; ++p) {
      int idx = t + p * 256;
      int rr = idx >> 4, cc = (idx & 15) * 4;   // rr = n-local, cc = k-local
      unsigned short h[4], l[4];
#pragma unroll
      for (int q = 0; q < 4; ++q) {
        float f = Ts[cc + q][rr];
        h[q] = f2bf(f);
        l[q] = f2bf(f - bf2f(h[q]));
      }
      size_t o = (size_t)(n0 + rr) * H_ + k0 + cc;
      *(ushort4*)(Wth + o) = make_ushort4(h[0], h[1], h[2], h[3]);
      *(ushort4*)(Wtl + o) = make_ushort4(l[0], l[1], l[2], l[3]);
    }
  }
}

// ------- 3-term split-bf16 MFMA GEMM, 1:1 interleaved read/MFMA stream -------
// R7 structure kept (best: 164 us, MfmaUtil ~60%): 256x128 tile, 8 waves 4x2,
// 3 LDS buffers, counted vmcnt(6), asm ds_reads reg-double-buffered, AITER
// style interleave {2 ds_reads -> 6 MFMAs} x8 per tile.
#define TILE_USH 24576            // 48 KiB per buffer in ushorts
#define OFF_AH 0                  // byte offsets within buffer:
#define OFF_AL 8192               //   AH 0, AL 16384, BH 32768, BL 40960
#define OFF_BH 16384
#define OFF_BL 20480

#define DSREAD(dst, addr, OFFLIT) \
  asm volatile("ds_read_b128 %0, %1 offset:" OFFLIT : "=v"(dst) : "v"(addr))

#define MF3(I, J, CAH, CAL, CBH, CBL)                                                          \
  acc[I][J] = __builtin_amdgcn_mfma_f32_16x16x32_bf16(CAH[I], CBH[J], acc[I][J], 0, 0, 0);     \
  acc[I][J] = __builtin_amdgcn_mfma_f32_16x16x32_bf16(CAH[I], CBL[J], acc[I][J], 0, 0, 0);     \
  acc[I][J] = __builtin_amdgcn_mfma_f32_16x16x32_bf16(CAL[I], CBH[J], acc[I][J], 0, 0, 0);

#define SB __builtin_amdgcn_sched_barrier(0)

// interleaved tile: reads R-set (tile t+1) 2-at-a-time between 6-MFMA chunks
// consuming C-set (tile t)
#define TILE_ILV(RAH, RAL, RBH, RBL, CAH, CAL, CBH, CBL, off_ush)        \
  do {                                                                   \
    const unsigned _ab = aAb + (unsigned)(off_ush) * 2u;                 \
    const unsigned _bb = aBb + (unsigned)(off_ush) * 2u;                 \
    __builtin_amdgcn_s_setprio(1);                                       \
    DSREAD(RAH[0], _ab, "0");     DSREAD(RAH[1], _ab, "1024");     SB;   \
    MF3(0, 0, CAH, CAL, CBH, CBL) MF3(0, 1, CAH, CAL, CBH, CBL)    SB;   \
    DSREAD(RAH[2], _ab, "2048");  DSREAD(RAH[3], _ab, "3072");     SB;   \
    MF3(0, 2, CAH, CAL, CBH, CBL) MF3(0, 3, CAH, CAL, CBH, CBL)    SB;   \
    DSREAD(RAL[0], _ab, "16384"); DSREAD(RAL[1], _ab, "17408");    SB;   \
    MF3(1, 0, CAH, CAL, CBH, CBL) MF3(1, 1, CAH, CAL, CBH, CBL)    SB;   \
    DSREAD(RAL[2], _ab, "18432"); DSREAD(RAL[3], _ab, "19456");    SB;   \
    MF3(1, 2, CAH, CAL, CBH, CBL) MF3(1, 3, CAH, CAL, CBH, CBL)    SB;   \
    DSREAD(RBH[0], _bb, "32768"); DSREAD(RBH[1], _bb, "33792");    SB;   \
    MF3(2, 0, CAH, CAL, CBH, CBL) MF3(2, 1, CAH, CAL, CBH, CBL)    SB;   \
    DSREAD(RBH[2], _bb, "34816"); DSREAD(RBH[3], _bb, "35840");    SB;   \
    MF3(2, 2, CAH, CAL, CBH, CBL) MF3(2, 3, CAH, CAL, CBH, CBL)    SB;   \
    DSREAD(RBL[0], _bb, "40960"); DSREAD(RBL[1], _bb, "41984");    SB;   \
    MF3(3, 0, CAH, CAL, CBH, CBL) MF3(3, 1, CAH, CAL, CBH, CBL)    SB;   \
    DSREAD(RBL[2], _bb, "43008"); DSREAD(RBL[3], _bb, "44032");    SB;   \
    MF3(3, 2, CAH, CAL, CBH, CBL) MF3(3, 3, CAH, CAL, CBH, CBL)    SB;   \
    __builtin_amdgcn_s_setprio(0);                                       \
  } while (0)

#define LOADSET_ASM(AH, AL, BH, BL, off_ush)                      \
  do {                                                            \
    unsigned _ab = aAb + (unsigned)(off_ush) * 2u;                \
    unsigned _bb = aBb + (unsigned)(off_ush) * 2u;                \
    DSREAD(AH[0], _ab, "0");     DSREAD(AH[1], _ab, "1024");      \
    DSREAD(AH[2], _ab, "2048");  DSREAD(AH[3], _ab, "3072");      \
    DSREAD(AL[0], _ab, "16384"); DSREAD(AL[1], _ab, "17408");     \
    DSREAD(AL[2], _ab, "18432"); DSREAD(AL[3], _ab, "19456");     \
    DSREAD(BH[0], _bb, "32768"); DSREAD(BH[1], _bb, "33792");     \
    DSREAD(BH[2], _bb, "34816"); DSREAD(BH[3], _bb, "35840");     \
    DSREAD(BL[0], _bb, "40960"); DSREAD(BL[1], _bb, "41984");     \
    DSREAD(BL[2], _bb, "43008"); DSREAD(BL[3], _bb, "44032");     \
  } while (0)

#define MFMASET(AH, AL, BH, BL)                                                                  \
  do {                                                                                           \
    __builtin_amdgcn_s_setprio(1);                                                               \
    _Pragma("unroll") for (int i = 0; i < 4; ++i)                                                \
        _Pragma("unroll") for (int j = 0; j < 4; ++j) {                                          \
      acc[i][j] = __builtin_amdgcn_mfma_f32_16x16x32_bf16(AH[i], BH[j], acc[i][j], 0, 0, 0);     \
      acc[i][j] = __builtin_amdgcn_mfma_f32_16x16x32_bf16(AH[i], BL[j], acc[i][j], 0, 0, 0);     \
      acc[i][j] = __builtin_amdgcn_mfma_f32_16x16x32_bf16(AL[i], BH[j], acc[i][j], 0, 0, 0);     \
    }                                                                                            \
    __builtin_amdgcn_s_setprio(0);                                                               \
  } while (0)

__global__ __launch_bounds__(512, 2) void k_gemm3(
    const unsigned short* __restrict__ Ah, const unsigned short* __restrict__ Al,
    const unsigned short* __restrict__ Bh, const unsigned short* __restrict__ Bl,
    unsigned short* __restrict__ Eh, unsigned short* __restrict__ El) {
  __shared__ unsigned short lds[3 * TILE_USH];
  const int t = threadIdx.x;
  const int lane = t & 63, wid = t >> 6;     // 8 waves
  const int wm = wid >> 1, wn = wid & 1;     // 4x2 wave grid, wave tile 64x64
  const int l16 = lane & 15, quad = lane >> 4;

  // bijective XCD remap of the 512-block grid
  const int lin = blockIdx.x + (blockIdx.y << 5);
  const int xcd = lin & 7, slot = lin >> 3;
  const int bm = ((xcd >> 1) << 3) + (slot >> 3);   // 0..31
  const int bn = ((xcd & 1) << 3) + (slot & 7);     // 0..15

  // staging addresses (pre-swizzled global source, linear LDS dest)
  const int rl = lane >> 2;
  const int gg8 = (((lane & 3) ^ ((rl >> 1) & 3)) << 3);
  const unsigned short* gAh0 = Ah + (size_t)(bm * 256 + wid * 16 + rl) * H_ + gg8;
  const unsigned short* gAl0 = Al + (size_t)(bm * 256 + wid * 16 + rl) * H_ + gg8;
  const unsigned short* gAh1 = gAh0 + (size_t)128 * H_;
  const unsigned short* gAl1 = gAl0 + (size_t)128 * H_;
  const unsigned short* gBh  = Bh + (size_t)(bn * 128 + wid * 16 + rl) * H_ + gg8;
  const unsigned short* gBl  = Bl + (size_t)(bn * 128 + wid * 16 + rl) * H_ + gg8;
  const int dA0 = wid * 512;        // chunk = 16 rows * 32 ushorts = 1 KiB
  const int dA1 = dA0 + 4096;       // chunk wid+8
  const int dB  = wid * 512;

  // read-side swizzled fragment offsets (ushort units, 0-conflict pattern)
  const int colq = ((quad ^ ((l16 >> 1) & 3)) << 3);
  const int rA = (wm * 64 + l16) * 32 + colq;
  const int rB = (wn * 64 + l16) * 32 + colq;
  // byte addresses for asm ds_read (generic LDS ptr low 32 bits = LDS offset)
  const unsigned ldsb = (unsigned)(uintptr_t)&lds[0];
  const unsigned aAb = ldsb + (unsigned)rA * 2u;
  const unsigned aBb = ldsb + (unsigned)rB * 2u;

  f32x4 acc[4][4];
#pragma unroll
  for (int i = 0; i < 4; ++i)
#pragma unroll
    for (int j = 0; j < 4; ++j) acc[i][j] = (f32x4)0.f;

  auto stage6 = [&](int bo, int k) {
    glds16(gAh0 + k, &lds[bo + OFF_AH + dA0]);
    glds16(gAh1 + k, &lds[bo + OFF_AH + dA1]);
    glds16(gAl0 + k, &lds[bo + OFF_AL + dA0]);
    glds16(gAl1 + k, &lds[bo + OFF_AL + dA1]);
    glds16(gBh + k,  &lds[bo + OFF_BH + dB]);
    glds16(gBl + k,  &lds[bo + OFF_BL + dB]);
  };

  // prologue: tiles 0,1 in flight; wait tile 0; asm-load its fragments
  stage6(0, 0);
  stage6(TILE_USH, 32);
  asm volatile("s_waitcnt vmcnt(6)" ::: "memory");
  __builtin_amdgcn_s_barrier();
  __builtin_amdgcn_sched_barrier(0);

  bf16x8 ahA[4], alA[4], bhA[4], blA[4];
  bf16x8 ahB[4], alB[4], bhB[4], blB[4];
  LOADSET_ASM(ahA, alA, bhA, blA, 0);

  int stage_off = 2 * TILE_USH;   // buffer of tile tt+2 at iter tt
  int read_off  = TILE_USH;       // buffer of tile tt+1 at iter tt

#pragma unroll 1
  for (int tt = 0; tt < 62; tt += 2) {
    // ---- tile tt: stage tt+2; interleave {reads of tt+1 (B-set)} with
    //      {MFMAs of tt (A-set)} ----
    stage6(stage_off, (tt + 2) * 32);
    stage_off += TILE_USH; if (stage_off == 3 * TILE_USH) stage_off = 0;
    asm volatile("s_waitcnt vmcnt(6) lgkmcnt(0)" ::: "memory");
    __builtin_amdgcn_s_barrier();
    __builtin_amdgcn_sched_barrier(0);
    TILE_ILV(ahB, alB, bhB, blB, ahA, alA, bhA, blA, read_off);
    read_off += TILE_USH; if (read_off == 3 * TILE_USH) read_off = 0;
    // ---- tile tt+1: stage tt+3; reads of tt+2 (A-set) vs MFMAs of tt+1 ----
    stage6(stage_off, (tt + 3) * 32);
    stage_off += TILE_USH; if (stage_off == 3 * TILE_USH) stage_off = 0;
    asm volatile("s_waitcnt vmcnt(6) lgkmcnt(0)" ::: "memory");
    __builtin_amdgcn_s_barrier();
    __builtin_amdgcn_sched_barrier(0);
    TILE_ILV(ahA, alA, bhA, blA, ahB, alB, bhB, blB, read_off);
    read_off += TILE_USH; if (read_off == 3 * TILE_USH) read_off = 0;
  }

  // tile 62: drain everything, issue reads for tile 63, MFMA A-set
  asm volatile("s_waitcnt vmcnt(0) lgkmcnt(0)" ::: "memory");
  __builtin_amdgcn_s_barrier();
  __builtin_amdgcn_sched_barrier(0);
  LOADSET_ASM(ahB, alB, bhB, blB, read_off);
  __builtin_amdgcn_sched_barrier(0);
  MFMASET(ahA, alA, bhA, blA);
  // tile 63: wait its asm reads, then MFMA B-set
  asm volatile("s_waitcnt lgkmcnt(0)" ::: "memory");
  __builtin_amdgcn_sched_barrier(0);
  MFMASET(ahB, alB, bhB, blB);

  // epilogue: split-bf16 store of E
#pragma unroll
  for (int i = 0; i < 4; ++i) {
    const int row0 = bm * 256 + wm * 64 + i * 16 + quad * 4;
#pragma unroll
    for (int j = 0; j < 4; ++j) {
      const int col = bn * 128 + wn * 64 + j * 16 + l16;
#pragma unroll
      for (int r = 0; r < 4; ++r) {
        float v = acc[i][j][r];
        unsigned short hh = f2bf(v);
        unsigned short ll = f2bf(v - bf2f(hh));
        Eh[(size_t)(row0 + r) * H_ + col] = hh;
        El[(size_t)(row0 + r) * H_ + col] = ll;
      }
    }
  }
}

// ---- MFMA Gram partials: G4[kc][c] = Eh*Eh^T + Eh*El^T + El*Eh^T over K
//      chunk kc. R8: PLAIN STORES (no atomics -- R7 showed atomics are a
//      first-order cost). out2 sums the 4 partials. 4-way K-split, 2-buffer
//      stage-ahead (R5/R6 best gram structure). ----
__global__ __launch_bounds__(256, 4) void k_gram_mfma(
    const unsigned short* __restrict__ Eh, const unsigned short* __restrict__ El,
    float* __restrict__ G4) {
  __shared__ unsigned short sb[2][16384];   // per buffer: H 8192, L 8192
  const int t = threadIdx.x;
  const int kc = blockIdx.x;   // 0..3, each covers K chunks 2*kc, 2*kc+1
  const int cc = blockIdx.y;   // capsule
  const int lane = t & 63, wid = t >> 6;
  const int wm = wid >> 1, wn = wid & 1;
  const int l16 = lane & 15, quad = lane >> 4;

  const int rl = lane >> 2;
  const int gg = (lane & 3) ^ ((rl >> 1) & 3);
  const int c0 = wid * 2, c1 = c0 + 1;
  const unsigned short* gH0 = Eh + (size_t)(cc * 128 + c0 * 16 + rl) * H_ + gg * 8;
  const unsigned short* gH1 = Eh + (size_t)(cc * 128 + c1 * 16 + rl) * H_ + gg * 8;
  const unsigned short* gL0 = El + (size_t)(cc * 128 + c0 * 16 + rl) * H_ + gg * 8;
  const unsigned short* gL1 = El + (size_t)(cc * 128 + c1 * 16 + rl) * H_ + gg * 8;
  const int dH0 = c0 * 512, dH1 = c1 * 512;

  const int swz = ((l16 >> 1) & 3);
  const int colq = ((quad ^ swz) * 8);

  f32x4 acc[4][4];
#pragma unroll
  for (int i = 0; i < 4; ++i)
#pragma unroll
    for (int j = 0; j < 4; ++j) acc[i][j] = (f32x4)0.f;

  auto stage4 = [&](int buf, int k) {
    glds16(gH0 + k, &sb[buf][dH0]);
    glds16(gH1 + k, &sb[buf][dH1]);
    glds16(gL0 + k, &sb[buf][8192 + dH0]);
    glds16(gL1 + k, &sb[buf][8192 + dH1]);
  };

  const int kbeg = kc * 512;           // two 256-wide chunks = 512
  stage4(0, kbeg);
  asm volatile("s_waitcnt vmcnt(0)" ::: "memory");
  __builtin_amdgcn_s_barrier();

  int cur = 0;
#pragma unroll 1
  for (int s = 0; s < 16; ++s) {
    if (s < 15) stage4(cur ^ 1, kbeg + (s + 1) * 32);
    const unsigned short* sH = &sb[cur][0];
    const unsigned short* sL = &sb[cur][8192];
    bf16x8 ah[4], al[4], bh[4], bl[4];
#pragma unroll
    for (int i = 0; i < 4; ++i) {
      const int ra = (wm * 64 + i * 16 + l16) * 32;
      const int rb = (wn * 64 + i * 16 + l16) * 32;
      ah[i] = *(const bf16x8*)&sH[ra + colq];
      al[i] = *(const bf16x8*)&sL[ra + colq];
      bh[i] = *(const bf16x8*)&sH[rb + colq];
      bl[i] = *(const bf16x8*)&sL[rb + colq];
    }
    __builtin_amdgcn_s_setprio(1);
#pragma unroll
    for (int i = 0; i < 4; ++i)
#pragma unroll
      for (int j = 0; j < 4; ++j) {
        acc[i][j] = __builtin_amdgcn_mfma_f32_16x16x32_bf16(ah[i], bh[j], acc[i][j], 0, 0, 0);
        acc[i][j] = __builtin_amdgcn_mfma_f32_16x16x32_bf16(ah[i], bl[j], acc[i][j], 0, 0, 0);
        acc[i][j] = __builtin_amdgcn_mfma_f32_16x16x32_bf16(al[i], bh[j], acc[i][j], 0, 0, 0);
      }
    __builtin_amdgcn_s_setprio(0);
    if (s < 15) {
      asm volatile("s_waitcnt vmcnt(0) lgkmcnt(0)" ::: "memory");
      __builtin_amdgcn_s_barrier();
    }
    cur ^= 1;
  }

  float* Gp = G4 + ((size_t)(kc * 64 + cc)) * (S_ * S_);
#pragma unroll
  for (int i = 0; i < 4; ++i) {
    const int row0 = wm * 64 + i * 16 + quad * 4;
#pragma unroll
    for (int j = 0; j < 4; ++j) {
      const int col = wn * 64 + j * 16 + l16;
#pragma unroll
      for (int r = 0; r < 4; ++r)
        Gp[(row0 + r) * S_ + col] = acc[i][j][r];
    }
  }
}

// ---- fused routing + projection. R8: sum the 4 G partials into a 64 KiB
//      LDS copy once per block, run the routing loop from LDS (global G
//      reads removed from the 3x128-step hot loop), 4-acc unroll to cut the
//      serial fmaf chain 128->32 deep. ----
__global__ void k_out2(const unsigned short* __restrict__ Eh,
                       const unsigned short* __restrict__ El,
                       const float* __restrict__ G4, float* __restrict__ out) {
  const int c = blockIdx.y;
  const int t = threadIdx.x;
  const int s = t & 127;
  __shared__ float Gl[128 * 128];
  __shared__ float dsh[128];
  __shared__ float red[128];
  __shared__ float wsh[128];

  // sum 4 partials into LDS (L2-resident reads, coalesced)
  {
    const float* g0 = G4 + ((size_t)(0 * 64 + c)) * 16384;
    const float* g1 = G4 + ((size_t)(1 * 64 + c)) * 16384;
    const float* g2 = G4 + ((size_t)(2 * 64 + c)) * 16384;
    const float* g3 = G4 + ((size_t)(3 * 64 + c)) * 16384;
#pragma unroll 8
    for (int e = t; e < 16384; e += 256)
      Gl[e] = (g0[e] + g1[e]) + (g2[e] + g3[e]);
  }
  __syncthreads();

  float b = 0.f;
  for (int it = 0; it < 3; ++it) {
    red[s] = b; __syncthreads();
    for (int off = 64; off > 0; off >>= 1) {
      if (s < off) red[s] = fmaxf(red[s], red[s + off]);
      __syncthreads();
    }
    float mx = red[0]; __syncthreads();
    float ev = expf(b - mx);
    red[s] = ev; __syncthreads();
    for (int off = 64; off > 0; off >>= 1) {
      if (s < off) red[s] = red[s] + red[s + off];
      __syncthreads();
    }
    float Z = red[0]; __syncthreads();
    float d = ev / Z;
    dsh[s] = d; __syncthreads();
    // (G d)_s from LDS, 4 independent accumulators
    float y0 = 0.f, y1 = 0.f, y2 = 0.f, y3 = 0.f;
#pragma unroll 8
    for (int j = 0; j < S_; j += 4) {
      y0 = fmaf(Gl[(j + 0) * S_ + s], dsh[j + 0], y0);
      y1 = fmaf(Gl[(j + 1) * S_ + s], dsh[j + 1], y1);
      y2 = fmaf(Gl[(j + 2) * S_ + s], dsh[j + 2], y2);
      y3 = fmaf(Gl[(j + 3) * S_ + s], dsh[j + 3], y3);
    }
    float y = (y0 + y1) + (y2 + y3);
    red[s] = d * y; __syncthreads();
    for (int off = 64; off > 0; off >>= 1) {
      if (s < off) red[s] = red[s] + red[s + off];
      __syncthreads();
    }
    float sq = red[0]; __syncthreads();
    float coeff = sq / (1.f + sq) / sqrtf(sq + 1e-9f);
    if (it == 2) wsh[s] = coeff * d;
    else b += coeff * y;
  }
  __syncthreads();

  // projection: out[c,h] = sum_s wsh[s] * (Eh+El)[c,s,h], 2 h per thread
  const int h2 = blockIdx.x * 256 + threadIdx.x;   // dword index, grid.x = 4
  const unsigned* Ph = (const unsigned*)(Eh + (size_t)c * S_ * H_) + h2;
  const unsigned* Pl = (const unsigned*)(El + (size_t)c * S_ * H_) + h2;
  float a0 = 0.f, a1 = 0.f;
#pragma unroll 8
  for (int ss = 0; ss < S_; ++ss) {
    unsigned uh = Ph[(size_t)ss * (H_ / 2)];
    unsigned ul = Pl[(size_t)ss * (H_ / 2)];
    a0 = fmaf(wsh[ss], bf2f((unsigned short)uh) + bf2f((unsigned short)ul), a0);
    a1 = fmaf(wsh[ss], bf2f((unsigned short)(uh >> 16)) + bf2f((unsigned short)(ul >> 16)), a1);
  }
  ((float2*)(out + (size_t)c * H_))[h2] = make_float2(a0, a1);
}

extern "C" void kernel_launch(void* const* d_in, const int* in_sizes, int n_in,
                              void* d_out, int out_size, void* d_ws, size_t ws_size,
                              hipStream_t stream) {
  (void)in_sizes; (void)n_in; (void)out_size; (void)ws_size;
  const float* x = (const float*)d_in[0];
  const float* W = (const float*)d_in[1];
  float* out = (float*)d_out;
  char* ws = (char*)d_ws;

  unsigned short* xh  = (unsigned short*)(ws);                 // 32 MiB
  unsigned short* xl  = (unsigned short*)(ws + 33554432);      // 32 MiB
  unsigned short* Wth = (unsigned short*)(ws + 67108864);      // 8 MiB
  unsigned short* Wtl = (unsigned short*)(ws + 75497472);      // 8 MiB
  unsigned short* Eh  = (unsigned short*)(ws + 83886080);      // 32 MiB
  unsigned short* El  = (unsigned short*)(ws + 117440512);     // 32 MiB
  // G4 partials (16 MiB) alias xh: xh is dead after k_gemm3, and stream
  // order guarantees split->gemm->gram->out2 within each iteration.
  float*          G4  = (float*)(ws);

  k_split_all<<<dim3(17408), 256, 0, stream>>>(x, xh, xl, W, Wth, Wtl);
  k_gemm3<<<dim3(32, 16), 512, 0, stream>>>(xh, xl, Wth, Wtl, Eh, El);
  k_gram_mfma<<<dim3(4, 64), 256, 0, stream>>>(Eh, El, G4);
  k_out2<<<dim3(4, 64), 256, 0, stream>>>(Eh, El, G4, out);
}